// Round 2
// baseline (117.504 us; speedup 1.0000x reference)
//
#include <hip/hip_runtime.h>
#include <math.h>

namespace {
constexpr int kB = 524288;
constexpr int kC = 128;
constexpr int kBlocks = 2048;
constexpr int kThreads = 256;
constexpr int kWavesPerBlock = kThreads / 64;
constexpr int kHalves = kBlocks * kWavesPerBlock * 2;  // 16384 half-waves
constexpr int kUnroll = 4;
constexpr int kIters = kB / (kHalves * kUnroll);  // 8
static_assert(kB % (kHalves * kUnroll) == 0, "exact tiling");

struct Partial {
  float sum;     // sum of t = y*log(x) over this block's rows (un-negated)
  float maxv;    // max of per-row loss (-row_sum)
  int   maxidx;  // first index attaining maxv
  int   pad;
};

__device__ inline float row_from_elems(const float4& xv, const float4& yv) {
  float t0 = yv.x * __logf(xv.x);
  float t1 = yv.y * __logf(xv.y);
  float t2 = yv.z * __logf(xv.z);
  float t3 = yv.w * __logf(xv.w);
  // nansum semantics: NaN terms count as 0
  t0 = (t0 == t0) ? t0 : 0.0f;
  t1 = (t1 == t1) ? t1 : 0.0f;
  t2 = (t2 == t2) ? t2 : 0.0f;
  t3 = (t3 == t3) ? t3 : 0.0f;
  return (t0 + t1) + (t2 + t3);
}

__device__ inline float half_reduce(float r) {
  // reduce across the 32 lanes of this half-wave (masks 1..16 stay in-half)
#pragma unroll
  for (int m = 1; m <= 16; m <<= 1) r += __shfl_xor(r, m, 64);
  return r;
}
}  // namespace

__global__ __launch_bounds__(kThreads) void nll_stage1(
    const float* __restrict__ x, const float* __restrict__ y,
    Partial* __restrict__ part) {
  const int tid = threadIdx.x;
  const int waveInBlock = tid >> 6;
  const int half = (tid >> 5) & 1;
  const int lane32 = tid & 31;
  const int halfId = (blockIdx.x * kWavesPerBlock + waveInBlock) * 2 + half;

  float lsum = 0.0f;        // thread-local sum of t
  float bestv = -INFINITY;  // running row-loss max
  int bestidx = 0x7fffffff;

#pragma unroll 1
  for (int it = 0; it < kIters; ++it) {
    const int r0 = halfId + (it * kUnroll + 0) * kHalves;
    const int r1 = halfId + (it * kUnroll + 1) * kHalves;
    const int r2 = halfId + (it * kUnroll + 2) * kHalves;
    const int r3 = halfId + (it * kUnroll + 3) * kHalves;

    // Issue all 8 x 16B loads before any compute: 4x MLP vs previous.
    const float4 xv0 = *((const float4*)(x + (size_t)r0 * kC) + lane32);
    const float4 yv0 = *((const float4*)(y + (size_t)r0 * kC) + lane32);
    const float4 xv1 = *((const float4*)(x + (size_t)r1 * kC) + lane32);
    const float4 yv1 = *((const float4*)(y + (size_t)r1 * kC) + lane32);
    const float4 xv2 = *((const float4*)(x + (size_t)r2 * kC) + lane32);
    const float4 yv2 = *((const float4*)(y + (size_t)r2 * kC) + lane32);
    const float4 xv3 = *((const float4*)(x + (size_t)r3 * kC) + lane32);
    const float4 yv3 = *((const float4*)(y + (size_t)r3 * kC) + lane32);

    const float p0 = row_from_elems(xv0, yv0);
    const float p1 = row_from_elems(xv1, yv1);
    const float p2 = row_from_elems(xv2, yv2);
    const float p3 = row_from_elems(xv3, yv3);
    lsum += (p0 + p1) + (p2 + p3);

    // Four independent shuffle chains — scheduler interleaves them.
    const float rowv0 = -half_reduce(p0);
    const float rowv1 = -half_reduce(p1);
    const float rowv2 = -half_reduce(p2);
    const float rowv3 = -half_reduce(p3);

    // r0<r1<r2<r3 and strictly increasing across iterations:
    // strict '>' update keeps the FIRST index attaining the max.
    if (rowv0 > bestv) { bestv = rowv0; bestidx = r0; }
    if (rowv1 > bestv) { bestv = rowv1; bestidx = r1; }
    if (rowv2 > bestv) { bestv = rowv2; bestidx = r2; }
    if (rowv3 > bestv) { bestv = rowv3; bestidx = r3; }
  }

  // wave-level reduce (64 lanes)
#pragma unroll
  for (int m = 1; m <= 32; m <<= 1) {
    lsum += __shfl_xor(lsum, m, 64);
    const float ov = __shfl_xor(bestv, m, 64);
    const int oi = __shfl_xor(bestidx, m, 64);
    if (ov > bestv || (ov == bestv && oi < bestidx)) {
      bestv = ov;
      bestidx = oi;
    }
  }

  __shared__ float s_sum[kWavesPerBlock];
  __shared__ float s_max[kWavesPerBlock];
  __shared__ int s_idx[kWavesPerBlock];
  if ((tid & 63) == 0) {
    s_sum[waveInBlock] = lsum;
    s_max[waveInBlock] = bestv;
    s_idx[waveInBlock] = bestidx;
  }
  __syncthreads();
  if (tid == 0) {
    float bs = 0.0f;
    float bm = -INFINITY;
    int bi = 0x7fffffff;
#pragma unroll
    for (int w = 0; w < kWavesPerBlock; ++w) {
      bs += s_sum[w];
      if (s_max[w] > bm || (s_max[w] == bm && s_idx[w] < bi)) {
        bm = s_max[w];
        bi = s_idx[w];
      }
    }
    part[blockIdx.x].sum = bs;
    part[blockIdx.x].maxv = bm;
    part[blockIdx.x].maxidx = bi;
    part[blockIdx.x].pad = 0;
  }
}

__global__ __launch_bounds__(64) void nll_stage2(
    const Partial* __restrict__ part, float* __restrict__ out) {
  const int lane = threadIdx.x;  // single wave
  double s = 0.0;
  float bm = -INFINITY;
  int bi = 0x7fffffff;
  for (int i = lane; i < kBlocks; i += 64) {
    const Partial p = part[i];
    s += (double)p.sum;
    if (p.maxv > bm || (p.maxv == bm && p.maxidx < bi)) {
      bm = p.maxv;
      bi = p.maxidx;
    }
  }
#pragma unroll
  for (int m = 1; m <= 32; m <<= 1) {
    s += __shfl_xor(s, m, 64);
    const float ov = __shfl_xor(bm, m, 64);
    const int oi = __shfl_xor(bi, m, 64);
    if (ov > bm || (ov == bm && oi < bi)) {
      bm = ov;
      bi = oi;
    }
  }
  if (lane == 0) {
    out[0] = (float)(-s / (double)kB);  // mean of per-row loss
    out[1] = bm;                        // max loss
    out[2] = (float)bi;                 // first argmax index
  }
}

extern "C" void kernel_launch(void* const* d_in, const int* in_sizes, int n_in,
                              void* d_out, int out_size, void* d_ws,
                              size_t ws_size, hipStream_t stream) {
  (void)in_sizes;
  (void)n_in;
  (void)out_size;
  (void)ws_size;
  const float* x = (const float*)d_in[0];
  const float* y = (const float*)d_in[1];
  float* out = (float*)d_out;
  Partial* part = (Partial*)d_ws;

  nll_stage1<<<kBlocks, kThreads, 0, stream>>>(x, y, part);
  nll_stage2<<<1, 64, 0, stream>>>(part, out);
}

// Round 3
// 115.849 us; speedup vs baseline: 1.0143x; 1.0143x over previous
//
#include <hip/hip_runtime.h>
#include <math.h>

namespace {
constexpr int kB = 524288;
constexpr int kC = 128;
constexpr int kBlocks = 4096;
constexpr int kThreads = 256;
constexpr int kWavesPerBlock = kThreads / 64;
constexpr int kHalves = kBlocks * kWavesPerBlock * 2;  // 32768 half-waves
constexpr int kIters = kB / kHalves;                   // 16 rows per half-wave
static_assert(kB % kHalves == 0, "exact tiling");

struct Partial {
  float sum;     // sum of t = y*log(x) over this block's rows (un-negated)
  float maxv;    // max of per-row loss (-row_sum)
  int   maxidx;  // first index attaining maxv
  int   pad;
};

__device__ inline float row_from_elems(const float4& xv, const float4& yv) {
  float t0 = yv.x * __logf(xv.x);
  float t1 = yv.y * __logf(xv.y);
  float t2 = yv.z * __logf(xv.z);
  float t3 = yv.w * __logf(xv.w);
  // nansum semantics: NaN terms count as 0
  t0 = (t0 == t0) ? t0 : 0.0f;
  t1 = (t1 == t1) ? t1 : 0.0f;
  t2 = (t2 == t2) ? t2 : 0.0f;
  t3 = (t3 == t3) ? t3 : 0.0f;
  return (t0 + t1) + (t2 + t3);
}

__device__ inline float half_reduce(float r) {
  // reduce across the 32 lanes of this half-wave (masks 1..16 stay in-half)
#pragma unroll
  for (int m = 1; m <= 16; m <<= 1) r += __shfl_xor(r, m, 64);
  return r;
}
}  // namespace

__global__ __launch_bounds__(kThreads) void nll_stage1(
    const float* __restrict__ x, const float* __restrict__ y,
    Partial* __restrict__ part) {
  const int tid = threadIdx.x;
  const int waveInBlock = tid >> 6;
  const int half = (tid >> 5) & 1;
  const int lane32 = tid & 31;
  const int halfId = (blockIdx.x * kWavesPerBlock + waveInBlock) * 2 + half;

  constexpr size_t kRowF4 = kC / 4;                      // 32 float4 per row
  constexpr size_t kStepF4 = (size_t)kHalves * kRowF4;   // row stride per iter

  const float4* xp = (const float4*)x + (size_t)halfId * kRowF4 + lane32;
  const float4* yp = (const float4*)y + (size_t)halfId * kRowF4 + lane32;

  float lsum = 0.0f;        // thread-local sum of t
  float bestv = -INFINITY;  // running row-loss max
  int bestidx = 0x7fffffff;

  // 2-deep software pipeline: next row's loads are issued BEFORE the
  // current row's compute + dependent shuffle chain.
  float4 cx = *xp;
  float4 cy = *yp;
  int row = halfId;
#pragma unroll 1
  for (int it = 0; it < kIters - 1; ++it) {
    xp += kStepF4;
    yp += kStepF4;
    const float4 nx = *xp;   // prefetch next row (no dependency on compute)
    const float4 ny = *yp;

    const float p = row_from_elems(cx, cy);
    lsum += p;
    const float rowv = -half_reduce(p);
    // rows strictly increase: strict '>' keeps the FIRST max index
    if (rowv > bestv) { bestv = rowv; bestidx = row; }
    row += kHalves;

    cx = nx;
    cy = ny;
  }
  {  // epilogue: last row
    const float p = row_from_elems(cx, cy);
    lsum += p;
    const float rowv = -half_reduce(p);
    if (rowv > bestv) { bestv = rowv; bestidx = row; }
  }

  // wave-level reduce (64 lanes)
#pragma unroll
  for (int m = 1; m <= 32; m <<= 1) {
    lsum += __shfl_xor(lsum, m, 64);
    const float ov = __shfl_xor(bestv, m, 64);
    const int oi = __shfl_xor(bestidx, m, 64);
    if (ov > bestv || (ov == bestv && oi < bestidx)) {
      bestv = ov;
      bestidx = oi;
    }
  }

  __shared__ float s_sum[kWavesPerBlock];
  __shared__ float s_max[kWavesPerBlock];
  __shared__ int s_idx[kWavesPerBlock];
  if ((tid & 63) == 0) {
    s_sum[waveInBlock] = lsum;
    s_max[waveInBlock] = bestv;
    s_idx[waveInBlock] = bestidx;
  }
  __syncthreads();
  if (tid == 0) {
    float bs = 0.0f;
    float bm = -INFINITY;
    int bi = 0x7fffffff;
#pragma unroll
    for (int w = 0; w < kWavesPerBlock; ++w) {
      bs += s_sum[w];
      if (s_max[w] > bm || (s_max[w] == bm && s_idx[w] < bi)) {
        bm = s_max[w];
        bi = s_idx[w];
      }
    }
    part[blockIdx.x].sum = bs;
    part[blockIdx.x].maxv = bm;
    part[blockIdx.x].maxidx = bi;
    part[blockIdx.x].pad = 0;
  }
}

__global__ __launch_bounds__(64) void nll_stage2(
    const Partial* __restrict__ part, float* __restrict__ out) {
  const int lane = threadIdx.x;  // single wave
  double s = 0.0;
  float bm = -INFINITY;
  int bi = 0x7fffffff;
  for (int i = lane; i < kBlocks; i += 64) {
    const Partial p = part[i];
    s += (double)p.sum;
    if (p.maxv > bm || (p.maxv == bm && p.maxidx < bi)) {
      bm = p.maxv;
      bi = p.maxidx;
    }
  }
#pragma unroll
  for (int m = 1; m <= 32; m <<= 1) {
    s += __shfl_xor(s, m, 64);
    const float ov = __shfl_xor(bm, m, 64);
    const int oi = __shfl_xor(bi, m, 64);
    if (ov > bm || (ov == bm && oi < bi)) {
      bm = ov;
      bi = oi;
    }
  }
  if (lane == 0) {
    out[0] = (float)(-s / (double)kB);  // mean of per-row loss
    out[1] = bm;                        // max loss
    out[2] = (float)bi;                 // first argmax index
  }
}

extern "C" void kernel_launch(void* const* d_in, const int* in_sizes, int n_in,
                              void* d_out, int out_size, void* d_ws,
                              size_t ws_size, hipStream_t stream) {
  (void)in_sizes;
  (void)n_in;
  (void)out_size;
  (void)ws_size;
  const float* x = (const float*)d_in[0];
  const float* y = (const float*)d_in[1];
  float* out = (float*)d_out;
  Partial* part = (Partial*)d_ws;

  nll_stage1<<<kBlocks, kThreads, 0, stream>>>(x, y, part);
  nll_stage2<<<1, 64, 0, stream>>>(part, out);
}